// Round 5
// baseline (126.310 us; speedup 1.0000x reference)
//
#include <hip/hip_runtime.h>

// ESRNN Holt-Winters: B=8192, T=1024, P=12.
// 256 blocks x 256 threads (4 waves), 32 series/block -> all 256 CUs active,
// half the per-CU memory traffic of the 128-block variant.
//   wave 0 (lanes 0-31): compute, 1 series/lane. Batched LDS: 4x ds_read_b128
//                        -> 16 pure-VALU steps -> 16 ds_write_b32. No vmem.
//   wave 1             : y stager (global_load_lds, 64-step chunks, dbuf).
//   waves 2-3          : writeback: 4x ds_read_b128 into regs FIRST, then 16
//                        independent coalesced 256B stores (no read->store
//                        dependent chain -- round-4's suspected binder).
// Pipeline (phase n): stage chunk n | compute chunk n-1 | store chunk n-2.
// LDS: ybuf 2*32*68 w + obuf 2*64*36 w = 35.8 KB.
//   ybuf[series][step]: stride 68 -> rows 16B-aligned (b128-able), banks
//     (4*lane + c)%32 on b128 reads, (r + lane)%32 on DMA writes: <=2-way.
//   obuf[step][series]: stride 36 -> rows 16B-aligned for storer b128 reads;
//     compute writes bank (lane + 4*step)%32: conflict-free.
// Seasonal ring s[12] + reciprocal ring rs[12] in registers, compile-time
// indices via template<int R> (chunk ring offset R0 = (4c)%12 in {0,4,8}).
// Divisions = 1-step Newton from previous reciprocal (measured absmax 0.0156
// across rounds 2-4, threshold 8.4e-2).

#define NS  32           // series per block
#define LSY 68           // y row stride (words): 64 steps + 4 pad
#define YBW (NS * LSY)
#define LSO 36           // o row stride (words): 32 series + 4 pad
#define OBW (64 * LSO)

typedef __attribute__((address_space(1))) const void* as1cv;
typedef __attribute__((address_space(3))) void* as3v;

// 16 ES steps starting at ring offset R (compile-time), chunk-local steps
// base..base+15. yb = per-lane y row, ob = obuf column base (+ lane).
template<int R>
__device__ __forceinline__ void batch16(
    const float* yb, float* ob, int base,
    float& l, float& bt, float& pn, float& rl, float* s, float* rs,
    float alpha, float oma, float beta, float nbeta, float ombphi,
    float gamma, float omg, float phi)
{
    const float4 q0 = *(const float4*)(yb + base + 0);
    const float4 q1 = *(const float4*)(yb + base + 4);
    const float4 q2 = *(const float4*)(yb + base + 8);
    const float4 q3 = *(const float4*)(yb + base + 12);
    const float yv[16] = {q0.x, q0.y, q0.z, q0.w, q1.x, q1.y, q1.z, q1.w,
                          q2.x, q2.y, q2.z, q2.w, q3.x, q3.y, q3.z, q3.w};
    float ov[16];
#pragma unroll
    for (int i = 0; i < 16; ++i) {
        const int J  = (R + i) % 12;      // constant after unroll
        const int Jn = (R + i + 1) % 12;
        const float yt = yv[i];
        const float ay = alpha * yt;
        const float a  = ay * rs[J];
        const float ln = fmaf(oma, pn, a);
        const float inner = fmaf(nbeta, l, ombphi * bt);
        const float bn  = fmaf(beta, ln, inner);
        const float pnn = fmaf(phi, bn, ln);
        rl = rl * fmaf(-ln, rl, 2.0f);          // Newton: rl ~= 1/ln
        const float gy = gamma * yt;
        const float c  = fmaf(gy, rl, omg * s[J]);
        s[J] = c;
        rs[J] = rs[J] * fmaf(-c, rs[J], 2.0f);  // Newton: rs ~= 1/c
        ov[i] = pnn * s[Jn];
        l = ln; bt = bn; pn = pnn;
    }
#pragma unroll
    for (int i = 0; i < 16; ++i) ob[(base + i) * LSO] = ov[i];
}

#define BATCH_ARGS l, bt, pn, rl, s, rs, alpha, oma, beta, nbeta, ombphi, gamma, omg, phi

__global__ __launch_bounds__(256) void esrnn_kernel(
    const float* __restrict__ y, const float* __restrict__ l0,
    const float* __restrict__ b0, const float* __restrict__ s0,
    const float* __restrict__ alpha_p, const float* __restrict__ beta_p,
    const float* __restrict__ phi_p, const float* __restrict__ gamma_p,
    float* __restrict__ out)
{
    __shared__ float ybuf[2 * YBW];
    __shared__ float obuf[2 * OBW];

    const int tid  = threadIdx.x;
    const int wid  = tid >> 6;
    const int lane = tid & 63;

    const float alpha = alpha_p[0];
    const float beta  = beta_p[0];
    const float phi   = phi_p[0];
    const float gamma = gamma_p[0];
    const float oma    = 1.0f - alpha;
    const float omg    = 1.0f - gamma;
    const float nbeta  = -beta;
    const float ombphi = (1.0f - beta) * phi;

    const float* yg = y + (size_t)blockIdx.x * NS * 1024;

    // Compute-wave state (dead regs in other waves / masked lanes).
    float l = 1.0f, bt = 0.0f, pn = 1.0f, rl = 1.0f;
    float s[12], rs[12];
#pragma unroll
    for (int k = 0; k < 12; ++k) { s[k] = 1.0f; rs[k] = 1.0f; }

    if (wid == 0 && lane < NS) {
        const int b = blockIdx.x * NS + lane;
        l  = l0[b];
        bt = b0[b];
        const float4 s03 = *(const float4*)(s0 + b * 12);
        const float4 s47 = *(const float4*)(s0 + b * 12 + 4);
        const float4 s8b = *(const float4*)(s0 + b * 12 + 8);
        s[0] = s03.x; s[1] = s03.y; s[2]  = s03.z; s[3]  = s03.w;
        s[4] = s47.x; s[5] = s47.y; s[6]  = s47.z; s[7]  = s47.w;
        s[8] = s8b.x; s[9] = s8b.y; s[10] = s8b.z; s[11] = s8b.w;
#pragma unroll
        for (int k = 0; k < 12; ++k) rs[k] = __builtin_amdgcn_rcpf(s[k]);
        rl = __builtin_amdgcn_rcpf(l);
        pn = fmaf(phi, bt, l);
    }

    for (int n = 0; n < 18; ++n) {
        if (wid == 1) {
            // ---- stager: chunk n -> ybuf[n&1] (32 rows, 256B coalesced ea) ----
            if (n <= 15) {
                const float* g = yg + n * 64 + lane;
                float* dst = ybuf + (size_t)(n & 1) * YBW;
#pragma unroll
                for (int r = 0; r < NS; ++r) {
                    __builtin_amdgcn_global_load_lds((as1cv)(g + r * 1024),
                                                     (as3v)(dst + r * LSY),
                                                     4, 0, 0);
                }
            }
        } else if (wid == 0) {
            // ---- compute: chunk c = n-1 from ybuf[c&1], o -> obuf[c&1] ----
            if (lane < NS && n >= 1 && n <= 16) {
                const int c = n - 1;
                const float* yb = ybuf + (size_t)(c & 1) * YBW + lane * LSY;
                float*       ob = obuf + (size_t)(c & 1) * OBW + lane;
                const int m = c % 3;   // chunk ring offset R0 = {0,4,8}
                if (m == 0) {
                    batch16<0>(yb, ob, 0,  BATCH_ARGS);
                    batch16<4>(yb, ob, 16, BATCH_ARGS);
                    batch16<8>(yb, ob, 32, BATCH_ARGS);
                    batch16<0>(yb, ob, 48, BATCH_ARGS);
                } else if (m == 1) {
                    batch16<4>(yb, ob, 0,  BATCH_ARGS);
                    batch16<8>(yb, ob, 16, BATCH_ARGS);
                    batch16<0>(yb, ob, 32, BATCH_ARGS);
                    batch16<4>(yb, ob, 48, BATCH_ARGS);
                } else {
                    batch16<8>(yb, ob, 0,  BATCH_ARGS);
                    batch16<0>(yb, ob, 16, BATCH_ARGS);
                    batch16<4>(yb, ob, 32, BATCH_ARGS);
                    batch16<8>(yb, ob, 48, BATCH_ARGS);
                }
            }
        } else {
            // ---- storer (waves 2,3): chunk c = n-2, 16 series each ----
            // lane = timestep within chunk; batch ALL LDS reads into regs
            // first (b128), then 16 independent coalesced 256B stores.
            if (n >= 2) {
                const int c = n - 2;
                const int sbase = (wid - 2) * 16;
                const float* obr = obuf + (size_t)(c & 1) * OBW
                                 + lane * LSO + sbase;
                float* og = out + (size_t)(blockIdx.x * NS + sbase) * 1024
                                + c * 64 + lane;
                float4 t0 = *(const float4*)(obr + 0);
                float4 t1 = *(const float4*)(obr + 4);
                float4 t2 = *(const float4*)(obr + 8);
                float4 t3 = *(const float4*)(obr + 12);
                og[ 0 * 1024] = t0.x; og[ 1 * 1024] = t0.y;
                og[ 2 * 1024] = t0.z; og[ 3 * 1024] = t0.w;
                og[ 4 * 1024] = t1.x; og[ 5 * 1024] = t1.y;
                og[ 6 * 1024] = t1.z; og[ 7 * 1024] = t1.w;
                og[ 8 * 1024] = t2.x; og[ 9 * 1024] = t2.y;
                og[10 * 1024] = t2.z; og[11 * 1024] = t2.w;
                og[12 * 1024] = t3.x; og[13 * 1024] = t3.y;
                og[14 * 1024] = t3.z; og[15 * 1024] = t3.w;
            }
        }
        __syncthreads();
    }
}

extern "C" void kernel_launch(void* const* d_in, const int* in_sizes, int n_in,
                              void* d_out, int out_size, void* d_ws, size_t ws_size,
                              hipStream_t stream) {
    const float* y     = (const float*)d_in[0];
    const float* l0    = (const float*)d_in[1];
    const float* b0    = (const float*)d_in[2];
    const float* s0    = (const float*)d_in[3];
    const float* alpha = (const float*)d_in[4];
    const float* beta  = (const float*)d_in[5];
    const float* phi   = (const float*)d_in[6];
    const float* gamma = (const float*)d_in[7];
    float* out = (float*)d_out;

    // 256 blocks x 32 series -> 1 block/CU on all 256 CUs.
    esrnn_kernel<<<dim3(256), dim3(256), 0, stream>>>(
        y, l0, b0, s0, alpha, beta, phi, gamma, out);
}

// Round 6
// 123.361 us; speedup vs baseline: 1.0239x; 1.0239x over previous
//
#include <hip/hip_runtime.h>

// ESRNN Holt-Winters: B=8192, T=1024, P=12.
// 256 blocks x 256 threads (4 waves), 32 series/block, 1 block/CU.
// NO in-loop __syncthreads: producer-consumer via LDS flags. Round-4/5
// showed a fixed ~6k-cyc lockstep phase floor independent of work; this
// removes the lockstep so each wave only waits on true data dependencies.
//   wave 0   : compute (lanes 0-31, 1 series/lane). 4x ds_read_b128 ->
//              16 pure-VALU steps -> 16 ds_write_b32 per batch. No vmem.
//   wave 1   : y stager, runs up to 4 chunks AHEAD (4-deep ybuf): HBM
//              latency fully pipelined off compute's critical path.
//              Explicit s_waitcnt vmcnt(0) before publishing (workgroup
//              release fence does NOT cover LDS-DMA completion).
//   waves 2-3: writeback, trail compute (4-deep obuf): 4x ds_read_b128 to
//              regs, then 16 coalesced 256B stores.
// Flags: sf (chunks staged), cf (chunks computed), wf2/wf3 (chunks stored).
//   compute(c): sf >= c+1, min(wf2,wf3) >= c-3
//   stager(n):  cf >= n-3        storer(c): cf >= c+1
// LDS: ybuf 4*32*68w (34.8KB) + obuf 4*64*36w (36.9KB) + flags = 71.7KB.
// All LDS patterns <=2-way bank aliasing (free on CDNA4; round-5 measured 0).
// Seasonal ring s[12]+rs[12] in registers, compile-time indices via
// template<int R>; chunk ring offset R0=(4c)%12 in {0,4,8}. Newton-reciprocal
// divisions (measured absmax 0.0156 across rounds 2-5, threshold 8.4e-2).

#define NS  32
#define LSY 68
#define YBW (NS * LSY)
#define LSO 36
#define OBW (64 * LSO)
#define NCHUNK 16

typedef __attribute__((address_space(1))) const void* as1cv;
typedef __attribute__((address_space(3))) void* as3v;

__device__ __forceinline__ int ld_flag(int* f) {
    return __hip_atomic_load(f, __ATOMIC_ACQUIRE, __HIP_MEMORY_SCOPE_WORKGROUP);
}
__device__ __forceinline__ void wait_ge(int* f, int target) {
    if (target <= 0) return;
    while (ld_flag(f) < target) {}
}
__device__ __forceinline__ void signal(int* f, int val, int lane) {
    if (lane == 0)
        __hip_atomic_store(f, val, __ATOMIC_RELEASE, __HIP_MEMORY_SCOPE_WORKGROUP);
}

template<int R>
__device__ __forceinline__ void batch16(
    const float* yb, float* ob, int base,
    float& l, float& bt, float& pn, float& rl, float* s, float* rs,
    float alpha, float oma, float beta, float nbeta, float ombphi,
    float gamma, float omg, float phi)
{
    const float4 q0 = *(const float4*)(yb + base + 0);
    const float4 q1 = *(const float4*)(yb + base + 4);
    const float4 q2 = *(const float4*)(yb + base + 8);
    const float4 q3 = *(const float4*)(yb + base + 12);
    const float yv[16] = {q0.x, q0.y, q0.z, q0.w, q1.x, q1.y, q1.z, q1.w,
                          q2.x, q2.y, q2.z, q2.w, q3.x, q3.y, q3.z, q3.w};
    float ov[16];
#pragma unroll
    for (int i = 0; i < 16; ++i) {
        const int J  = (R + i) % 12;
        const int Jn = (R + i + 1) % 12;
        const float yt = yv[i];
        const float ay = alpha * yt;
        const float a  = ay * rs[J];
        const float ln = fmaf(oma, pn, a);
        const float inner = fmaf(nbeta, l, ombphi * bt);
        const float bn  = fmaf(beta, ln, inner);
        const float pnn = fmaf(phi, bn, ln);
        rl = rl * fmaf(-ln, rl, 2.0f);          // Newton: rl ~= 1/ln
        const float gy = gamma * yt;
        const float c  = fmaf(gy, rl, omg * s[J]);
        s[J] = c;
        rs[J] = rs[J] * fmaf(-c, rs[J], 2.0f);  // Newton: rs ~= 1/c
        ov[i] = pnn * s[Jn];
        l = ln; bt = bn; pn = pnn;
    }
#pragma unroll
    for (int i = 0; i < 16; ++i) ob[(base + i) * LSO] = ov[i];
}

#define BATCH_ARGS l, bt, pn, rl, s, rs, alpha, oma, beta, nbeta, ombphi, gamma, omg, phi

__global__ __launch_bounds__(256) void esrnn_kernel(
    const float* __restrict__ y, const float* __restrict__ l0,
    const float* __restrict__ b0, const float* __restrict__ s0,
    const float* __restrict__ alpha_p, const float* __restrict__ beta_p,
    const float* __restrict__ phi_p, const float* __restrict__ gamma_p,
    float* __restrict__ out)
{
    __shared__ float ybuf[4 * YBW];
    __shared__ float obuf[4 * OBW];
    __shared__ int   flg[4];   // 0:sf staged  1:cf computed  2:wf2  3:wf3

    const int tid  = threadIdx.x;
    const int wid  = tid >> 6;
    const int lane = tid & 63;

    if (tid < 4) flg[tid] = 0;
    __syncthreads();           // one-time init barrier only

    const float* yg = y + (size_t)blockIdx.x * NS * 1024;

    if (wid == 1) {
        // ================= stager =================
        for (int n = 0; n < NCHUNK; ++n) {
            wait_ge(&flg[1], n - 3);               // ybuf[n&3] free?
            const float* g = yg + n * 64 + lane;
            float* dst = ybuf + (size_t)(n & 3) * YBW;
#pragma unroll
            for (int r = 0; r < NS; ++r) {
                __builtin_amdgcn_global_load_lds((as1cv)(g + r * 1024),
                                                 (as3v)(dst + r * LSY),
                                                 4, 0, 0);
            }
            __builtin_amdgcn_s_waitcnt(0x0f70);    // vmcnt(0): DMA landed
            signal(&flg[0], n + 1, lane);
        }
    } else if (wid == 0) {
        // ================= compute =================
        const float alpha = alpha_p[0];
        const float beta  = beta_p[0];
        const float phi   = phi_p[0];
        const float gamma = gamma_p[0];
        const float oma    = 1.0f - alpha;
        const float omg    = 1.0f - gamma;
        const float nbeta  = -beta;
        const float ombphi = (1.0f - beta) * phi;

        float l = 1.0f, bt = 0.0f, pn = 1.0f, rl = 1.0f;
        float s[12], rs[12];
#pragma unroll
        for (int k = 0; k < 12; ++k) { s[k] = 1.0f; rs[k] = 1.0f; }
        if (lane < NS) {
            const int b = blockIdx.x * NS + lane;
            l  = l0[b];
            bt = b0[b];
            const float4 s03 = *(const float4*)(s0 + b * 12);
            const float4 s47 = *(const float4*)(s0 + b * 12 + 4);
            const float4 s8b = *(const float4*)(s0 + b * 12 + 8);
            s[0] = s03.x; s[1] = s03.y; s[2]  = s03.z; s[3]  = s03.w;
            s[4] = s47.x; s[5] = s47.y; s[6]  = s47.z; s[7]  = s47.w;
            s[8] = s8b.x; s[9] = s8b.y; s[10] = s8b.z; s[11] = s8b.w;
#pragma unroll
            for (int k = 0; k < 12; ++k) rs[k] = __builtin_amdgcn_rcpf(s[k]);
            rl = __builtin_amdgcn_rcpf(l);
            pn = fmaf(phi, bt, l);
        }

        for (int c = 0; c < NCHUNK; ++c) {
            wait_ge(&flg[0], c + 1);               // y chunk c staged?
            // obuf[c&3] free? (storers done with chunk c-4)
            if (c >= 4) {
                const int tgt = c - 3;
                while (ld_flag(&flg[2]) < tgt || ld_flag(&flg[3]) < tgt) {}
            }
            if (lane < NS) {
                const float* yb = ybuf + (size_t)(c & 3) * YBW + lane * LSY;
                float*       ob = obuf + (size_t)(c & 3) * OBW + lane;
                const int m = c % 3;   // chunk ring offset R0 = {0,4,8}
                if (m == 0) {
                    batch16<0>(yb, ob, 0,  BATCH_ARGS);
                    batch16<4>(yb, ob, 16, BATCH_ARGS);
                    batch16<8>(yb, ob, 32, BATCH_ARGS);
                    batch16<0>(yb, ob, 48, BATCH_ARGS);
                } else if (m == 1) {
                    batch16<4>(yb, ob, 0,  BATCH_ARGS);
                    batch16<8>(yb, ob, 16, BATCH_ARGS);
                    batch16<0>(yb, ob, 32, BATCH_ARGS);
                    batch16<4>(yb, ob, 48, BATCH_ARGS);
                } else {
                    batch16<8>(yb, ob, 0,  BATCH_ARGS);
                    batch16<0>(yb, ob, 16, BATCH_ARGS);
                    batch16<4>(yb, ob, 32, BATCH_ARGS);
                    batch16<8>(yb, ob, 48, BATCH_ARGS);
                }
            }
            signal(&flg[1], c + 1, lane);
        }
    } else {
        // ================= storers (waves 2,3) =================
        int* myf = &flg[wid];                      // wf2 / wf3
        const int sbase = (wid - 2) * 16;
        for (int c = 0; c < NCHUNK; ++c) {
            wait_ge(&flg[1], c + 1);               // o chunk c computed?
            const float* obr = obuf + (size_t)(c & 3) * OBW
                             + lane * LSO + sbase;
            float* og = out + (size_t)(blockIdx.x * NS + sbase) * 1024
                            + c * 64 + lane;
            float4 t0 = *(const float4*)(obr + 0);
            float4 t1 = *(const float4*)(obr + 4);
            float4 t2 = *(const float4*)(obr + 8);
            float4 t3 = *(const float4*)(obr + 12);
            og[ 0 * 1024] = t0.x; og[ 1 * 1024] = t0.y;
            og[ 2 * 1024] = t0.z; og[ 3 * 1024] = t0.w;
            og[ 4 * 1024] = t1.x; og[ 5 * 1024] = t1.y;
            og[ 6 * 1024] = t1.z; og[ 7 * 1024] = t1.w;
            og[ 8 * 1024] = t2.x; og[ 9 * 1024] = t2.y;
            og[10 * 1024] = t2.z; og[11 * 1024] = t2.w;
            og[12 * 1024] = t3.x; og[13 * 1024] = t3.y;
            og[14 * 1024] = t3.z; og[15 * 1024] = t3.w;
            signal(myf, c + 1, lane);              // LDS reads done -> buffer free
        }
    }
}

extern "C" void kernel_launch(void* const* d_in, const int* in_sizes, int n_in,
                              void* d_out, int out_size, void* d_ws, size_t ws_size,
                              hipStream_t stream) {
    const float* y     = (const float*)d_in[0];
    const float* l0    = (const float*)d_in[1];
    const float* b0    = (const float*)d_in[2];
    const float* s0    = (const float*)d_in[3];
    const float* alpha = (const float*)d_in[4];
    const float* beta  = (const float*)d_in[5];
    const float* phi   = (const float*)d_in[6];
    const float* gamma = (const float*)d_in[7];
    float* out = (float*)d_out;

    esrnn_kernel<<<dim3(256), dim3(256), 0, stream>>>(
        y, l0, b0, s0, alpha, beta, phi, gamma, out);
}